// Round 1
// 1299.877 us; speedup vs baseline: 1.0077x; 1.0077x over previous
//
#include <hip/hip_runtime.h>

// Problem: x [1, 4096] f32, weights [512, 4096, 128] f32
// ret[o] = sum_{s,a} x[s] * w[o,s,a]  ==  sum_s x[s] * rowsum_a(w[o,s,:])
// Memory-bound: weights = 1 GiB streamed exactly once. Roofline ~170 us @ 6.3 TB/s.
//
// Layout: one block per output o (512 blocks x 1024 threads = 8192 waves =
// exact chip wave capacity; 2 blocks/CU, no tail). Each block streams its
// contiguous 2 MiB weight row, reduces in-block, and plain-stores out[o] --
// no atomics, no separate zero kernel, single dispatch in the graph.

#define OUT_DIM 512
#define NS 4096
#define NA 128
#define BLOCK 1024
#define F4_PER_O (NS * NA / 4)     // 131072 float4 per output row
#define ITERS (F4_PER_O / BLOCK)   // 128 float4 per thread

typedef float f32x4 __attribute__((ext_vector_type(4)));

__global__ __launch_bounds__(BLOCK) void lsh_reduce_kernel(
        const float* __restrict__ x,
        const float* __restrict__ w,
        float* __restrict__ out) {
    __shared__ float xs[NS];            // 16 KiB
    __shared__ float part[BLOCK / 64];  // 16 wave partials

    // Stage x into LDS: 1024 threads x 1 float4 = all 4096 samples, coalesced.
    ((f32x4*)xs)[threadIdx.x] = ((const f32x4*)x)[threadIdx.x];
    __syncthreads();

    const int o = blockIdx.x;
    const f32x4* __restrict__ w4 = (const f32x4*)(w + (size_t)o * (NS * NA));

    // NA=128 divisible by 4: every aligned float4 lies within one sample row
    // (32 float4 per sample), so all 4 elements share x[s], s = idx4 >> 5.
    // Per wave: lanes 0-31 read xs[s], lanes 32-63 read xs[s+1] -> broadcasts,
    // zero bank conflicts.
    float acc = 0.0f;
    #pragma unroll 8
    for (int i = 0; i < ITERS; ++i) {
        const int idx4 = i * BLOCK + (int)threadIdx.x;
        f32x4 v = w4[idx4];             // 64 lanes x 16 B = 1 KiB coalesced
        acc += (v.x + v.y + v.z + v.w) * xs[idx4 >> 5];
    }

    // wave(64) shuffle reduction
    #pragma unroll
    for (int off = 32; off > 0; off >>= 1)
        acc += __shfl_down(acc, off, 64);

    const int lane = threadIdx.x & 63;
    const int wave = threadIdx.x >> 6;
    if (lane == 0) part[wave] = acc;
    __syncthreads();
    if (threadIdx.x == 0) {
        float t = 0.0f;
        #pragma unroll
        for (int i = 0; i < BLOCK / 64; ++i) t += part[i];
        out[o] = t;                     // plain store overwrites poisoned d_out
    }
}

extern "C" void kernel_launch(void* const* d_in, const int* in_sizes, int n_in,
                              void* d_out, int out_size, void* d_ws, size_t ws_size,
                              hipStream_t stream) {
    const float* x = (const float*)d_in[0];
    const float* w = (const float*)d_in[1];
    float* out = (float*)d_out;
    lsh_reduce_kernel<<<OUT_DIM, BLOCK, 0, stream>>>(x, w, out);
}